// Round 7
// baseline (74.771 us; speedup 1.0000x reference)
//
#include <hip/hip_runtime.h>
#include <hip/hip_bf16.h>
#include <math.h>

// GConvLSTM cell via MFMA (graph inputs are dead code in the reference).
// Gate GEMM computed TRANSPOSED: g^T = W^T @ [x|h]^T via
// mfma_f32_16x16x32_bf16(A=W-fragment, B=X-fragment).
//   A[i=dim][k]  = W[k][gate*16+dim]   -> lane(i=q, kb) holds k=kb*8+e  (same
//                                         per-lane data as the old B-frag)
//   B[k][j=node] = X[node][k]          -> lane(j=q, kb) holds k=kb*8+e  (same
//                                         per-lane data as the old A-frag)
//   D[i=dim][j=node]: col=lane&15 -> node gb0+q, row=(lane>>4)*4+e -> dim kb*4+e
// So each lane owns ONE node and 4 CONSECUTIVE dims of every gate:
//   - c load is one float4 (wave-wide: 64 lanes x 16B = 1024B contiguous)
//   - h_new/c_new are float4 stores (same full coalescing)
//   - out-projection: in-lane 4-dot, then 2 shfl_xor (kb bits 4,5), lanes 0-15
//     store 64B coalesced
// W K-rows 24..31 are zero, so kb==3 B-garbage contributes 0 (R4-proven).
// R7 vs R6: swapped-operand layout (above); IW back to 8 (IW=4 regressed R6).
// d_out layout: [N] out | [N*16] h_new | [N*16] c_new.  Requires n % 16 == 0.

typedef short bf16x8 __attribute__((ext_vector_type(8)));
typedef float f32x4 __attribute__((ext_vector_type(4)));

#define LOG2E 1.44269504088896f

__device__ __forceinline__ float sig1(float v) {
    return __builtin_amdgcn_rcpf(1.0f + __builtin_amdgcn_exp2f(-LOG2E * v));
}
__device__ __forceinline__ float tanh1(float v) {
    return 1.0f - 2.0f * __builtin_amdgcn_rcpf(__builtin_amdgcn_exp2f((2.0f * LOG2E) * v) + 1.0f);
}
__device__ __forceinline__ f32x4 sig4(f32x4 v) {
    f32x4 r; r[0]=sig1(v[0]); r[1]=sig1(v[1]); r[2]=sig1(v[2]); r[3]=sig1(v[3]); return r;
}
__device__ __forceinline__ f32x4 tanh4(f32x4 v) {
    f32x4 r; r[0]=tanh1(v[0]); r[1]=tanh1(v[1]); r[2]=tanh1(v[2]); r[3]=tanh1(v[3]); return r;
}
__device__ __forceinline__ short f2bf(float f) {
    __bf16 b = (__bf16)f;          // pairs fuse to v_cvt_pk_bf16_f32
    short s; __builtin_memcpy(&s, &b, 2); return s;
}
__device__ __forceinline__ f32x4 max4z(f32x4 a) {
    f32x4 r; r[0]=fmaxf(a[0],0.f); r[1]=fmaxf(a[1],0.f); r[2]=fmaxf(a[2],0.f); r[3]=fmaxf(a[3],0.f); return r;
}

#define IW 8                       // 64-node tiles per block
#define NPB (64 * IW)              // 512 nodes per block

__global__ __launch_bounds__(256) void lstm_mfma_kernel(
    const float* __restrict__ x,       // N x 8
    const float* __restrict__ h,       // N x 16
    const float* __restrict__ c,       // N x 16
    const float* __restrict__ Wx,      // 8 x 64
    const float* __restrict__ bx,      // 64
    const float* __restrict__ Wh,      // 16 x 64
    const float* __restrict__ bh,      // 64
    const float* __restrict__ w_peep,  // 3 x 16
    const float* __restrict__ b_gates, // 4 x 16
    const float* __restrict__ W_lin,   // 16
    const float* __restrict__ b_lin,   // 1
    float* __restrict__ dout,
    int n)
{
    const int lane = threadIdx.x & 63;
    const int wave = threadIdx.x >> 6;
    const int q  = lane & 15;   // A-role: dim; B/D-role: node offset
    const int kb = lane >> 4;   // k-block (8 k's each); D-role: dim block

    // ---- weight A-fragment: wfrag[t][e] = W[kb*8+e][t*16+q], W = [Wx; Wh; 0pad]
    // Rows 24..31 MUST be exactly 0 (kb==3 X-frag is garbage and relies on it).
    bf16x8 wfrag[4];
    #pragma unroll
    for (int t = 0; t < 4; ++t) {
        #pragma unroll
        for (int e = 0; e < 8; ++e) {
            const int r = kb * 8 + e;
            float w = 0.0f;
            if (r < 8)        w = Wx[r * 64 + t * 16 + q];
            else if (r < 24)  w = Wh[(r - 8) * 64 + t * 16 + q];
            wfrag[t][e] = f2bf(w);
        }
    }

    // ---- per-lane epilogue constants for dims dd..dd+3 (b_gates folded in)
    const int dd = kb * 4;
    f32x4 biasI, biasF, biasC, biasO, pp0, pp1, pp2, wl4;
    #pragma unroll
    for (int e = 0; e < 4; ++e) {
        biasI[e] = bx[dd + e]      + bh[dd + e]      + b_gates[dd + e];
        biasF[e] = bx[16 + dd + e] + bh[16 + dd + e] + b_gates[16 + dd + e];
        biasC[e] = bx[32 + dd + e] + bh[32 + dd + e] + b_gates[32 + dd + e];
        biasO[e] = bx[48 + dd + e] + bh[48 + dd + e] + b_gates[48 + dd + e];
        pp0[e] = w_peep[dd + e]; pp1[e] = w_peep[16 + dd + e]; pp2[e] = w_peep[32 + dd + e];
        wl4[e] = W_lin[dd + e];
    }
    const float bl = b_lin[0];

    const unsigned blockBase = (unsigned)blockIdx.x * NPB;
    const unsigned gb0   = blockBase + (unsigned)wave * 16u;  // wave's first node
    const unsigned node0 = gb0 + (unsigned)q;

    // per-lane X pointer (B-frag): x rows for kb==0, h rows otherwise
    // (kb==3 loads h[...+0] = finite garbage; multiplied by zero W rows)
    const float* aptr;
    unsigned astride;
    if (kb == 0) { aptr = x + (size_t)node0 * 8;                        astride = 64u * 8;  }
    else         { aptr = h + (size_t)node0 * 16 + ((kb == 2) ? 8 : 0); astride = 64u * 16; }

    unsigned co = node0 * 16u + (unsigned)dd;  // c / h_new / c_new float4 offset
    unsigned ro = node0;                       // out offset (kb==0 lanes store)
    float* hob = dout + (size_t)n;        // h_new base
    float* cob = dout + (size_t)n * 17;   // c_new base

#define BODY                                                                   \
    {                                                                          \
        float4 a0 = *reinterpret_cast<const float4*>(aptr);                    \
        float4 a1 = *reinterpret_cast<const float4*>(aptr + 4);                \
        bf16x8 xf;                                                             \
        xf[0] = f2bf(a0.x); xf[1] = f2bf(a0.y);                                \
        xf[2] = f2bf(a0.z); xf[3] = f2bf(a0.w);                                \
        xf[4] = f2bf(a1.x); xf[5] = f2bf(a1.y);                                \
        xf[6] = f2bf(a1.z); xf[7] = f2bf(a1.w);                                \
        f32x4 accI = biasI, accF = biasF, accC = biasC, accO = biasO;          \
        accI = __builtin_amdgcn_mfma_f32_16x16x32_bf16(wfrag[0], xf, accI, 0, 0, 0); \
        accF = __builtin_amdgcn_mfma_f32_16x16x32_bf16(wfrag[1], xf, accF, 0, 0, 0); \
        accC = __builtin_amdgcn_mfma_f32_16x16x32_bf16(wfrag[2], xf, accC, 0, 0, 0); \
        accO = __builtin_amdgcn_mfma_f32_16x16x32_bf16(wfrag[3], xf, accO, 0, 0, 0); \
        f32x4 cv = *reinterpret_cast<const f32x4*>(c + co);                    \
        f32x4 iv = sig4(pp0 * cv + accI);                                      \
        f32x4 fv = sig4(pp1 * cv + accF);                                      \
        f32x4 tv = tanh4(accC);                                                \
        f32x4 cn = fv * cv + iv * tv;                                          \
        f32x4 ov = sig4(pp2 * cn + accO);                                      \
        f32x4 hn = ov * tanh4(cn);                                             \
        *reinterpret_cast<f32x4*>(hob + co) = hn;                              \
        *reinterpret_cast<f32x4*>(cob + co) = cn;                              \
        f32x4 rr = max4z(hn) * wl4;                                            \
        float os = (rr[0] + rr[1]) + (rr[2] + rr[3]);                          \
        os += __shfl_xor(os, 16);                                              \
        os += __shfl_xor(os, 32);                                              \
        if (kb == 0) dout[ro] = os + bl;                                       \
        aptr += astride; co += 1024u; ro += 64u;                               \
    }

    if (blockBase + NPB <= (unsigned)n) {
        // full block: exact trip count, no bounds checks; keep rolled for VGPR
        #pragma unroll 1
        for (int it = 0; it < IW; ++it) BODY
    } else {
        // tail block (at most one): group-granular bounds check (n % 16 == 0)
        #pragma unroll 1
        for (int it = 0; it < IW; ++it) {
            if (gb0 + (unsigned)(it * 64) >= (unsigned)n) break;
            BODY
        }
    }
#undef BODY
}

extern "C" void kernel_launch(void* const* d_in, const int* in_sizes, int n_in,
                              void* d_out, int out_size, void* d_ws, size_t ws_size,
                              hipStream_t stream) {
    const float* x       = (const float*)d_in[0];
    // d_in[1] = edge_index (int64, unused), d_in[2] = edge_attr (unused)
    const float* h       = (const float*)d_in[3];
    const float* c       = (const float*)d_in[4];
    const float* Wx      = (const float*)d_in[5];
    const float* bx      = (const float*)d_in[6];
    const float* Wh      = (const float*)d_in[7];
    const float* bh      = (const float*)d_in[8];
    const float* w_peep  = (const float*)d_in[9];
    const float* b_gates = (const float*)d_in[10];
    const float* W_lin   = (const float*)d_in[11];
    const float* b_lin   = (const float*)d_in[12];
    float* out = (float*)d_out;

    const int n = in_sizes[0] / 8;  // N = 1,000,000
    const int blocks = (n + NPB - 1) / NPB;
    lstm_mfma_kernel<<<blocks, 256, 0, stream>>>(
        x, h, c, Wx, bx, Wh, bh, w_peep, b_gates, W_lin, b_lin, out, n);
}

// Round 8
// 53.594 us; speedup vs baseline: 1.3951x; 1.3951x over previous
//
#include <hip/hip_runtime.h>
#include <hip/hip_bf16.h>
#include <math.h>

// GConvLSTM cell via MFMA (graph inputs are dead code in the reference).
// Transposed gate GEMM (R7 layout): g^T = W^T @ [x|h]^T via
// mfma_f32_16x16x32_bf16(A=W-frag, B=X-frag); lane (q=lane&15, kb=lane>>4)
// owns node gb0+q, dims kb*4..kb*4+3 of every gate -> all c/h_new/c_new
// accesses are wave-contiguous float4; out-reduce = in-lane 4-dot + 2 shfl.
// W K-rows 24..31 are zero, so kb==3 X-garbage contributes 0 (R4-proven).
// R8 vs R7: 1-deep SOFTWARE PIPELINE — iteration it+1's x/h and c loads are
// issued before iteration it's compute, so ~900cy HBM latency hides under
// MFMA+epilogue (grid is one residency round: wall time == per-wave latency).
// h_new/c_new stores are nontemporal (write-once data; stop evicting L3-hot
// inputs between graph replays).
// d_out layout: [N] out | [N*16] h_new | [N*16] c_new.  Requires n % 16 == 0.

typedef short bf16x8 __attribute__((ext_vector_type(8)));
typedef float f32x4 __attribute__((ext_vector_type(4)));

#define LOG2E 1.44269504088896f

__device__ __forceinline__ float sig1(float v) {
    return __builtin_amdgcn_rcpf(1.0f + __builtin_amdgcn_exp2f(-LOG2E * v));
}
__device__ __forceinline__ float tanh1(float v) {
    return 1.0f - 2.0f * __builtin_amdgcn_rcpf(__builtin_amdgcn_exp2f((2.0f * LOG2E) * v) + 1.0f);
}
__device__ __forceinline__ f32x4 sig4(f32x4 v) {
    f32x4 r; r[0]=sig1(v[0]); r[1]=sig1(v[1]); r[2]=sig1(v[2]); r[3]=sig1(v[3]); return r;
}
__device__ __forceinline__ f32x4 tanh4(f32x4 v) {
    f32x4 r; r[0]=tanh1(v[0]); r[1]=tanh1(v[1]); r[2]=tanh1(v[2]); r[3]=tanh1(v[3]); return r;
}
__device__ __forceinline__ short f2bf(float f) {
    __bf16 b = (__bf16)f;          // pairs fuse to v_cvt_pk_bf16_f32
    short s; __builtin_memcpy(&s, &b, 2); return s;
}
__device__ __forceinline__ f32x4 max4z(f32x4 a) {
    f32x4 r; r[0]=fmaxf(a[0],0.f); r[1]=fmaxf(a[1],0.f); r[2]=fmaxf(a[2],0.f); r[3]=fmaxf(a[3],0.f); return r;
}

#define IW 8                       // 64-node tiles per block
#define NPB (64 * IW)              // 512 nodes per block

__global__ __launch_bounds__(256) void lstm_mfma_kernel(
    const float* __restrict__ x,       // N x 8
    const float* __restrict__ h,       // N x 16
    const float* __restrict__ c,       // N x 16
    const float* __restrict__ Wx,      // 8 x 64
    const float* __restrict__ bx,      // 64
    const float* __restrict__ Wh,      // 16 x 64
    const float* __restrict__ bh,      // 64
    const float* __restrict__ w_peep,  // 3 x 16
    const float* __restrict__ b_gates, // 4 x 16
    const float* __restrict__ W_lin,   // 16
    const float* __restrict__ b_lin,   // 1
    float* __restrict__ dout,
    int n)
{
    const int lane = threadIdx.x & 63;
    const int wave = threadIdx.x >> 6;
    const int q  = lane & 15;   // A-role: dim; B/D-role: node offset
    const int kb = lane >> 4;   // k-block (8 k's each); D-role: dim block

    // ---- weight A-fragment: wfrag[t][e] = W[kb*8+e][t*16+q], W = [Wx; Wh; 0pad]
    // Rows 24..31 MUST be exactly 0 (kb==3 X-frag is garbage and relies on it).
    bf16x8 wfrag[4];
    #pragma unroll
    for (int t = 0; t < 4; ++t) {
        #pragma unroll
        for (int e = 0; e < 8; ++e) {
            const int r = kb * 8 + e;
            float w = 0.0f;
            if (r < 8)        w = Wx[r * 64 + t * 16 + q];
            else if (r < 24)  w = Wh[(r - 8) * 64 + t * 16 + q];
            wfrag[t][e] = f2bf(w);
        }
    }

    // ---- per-lane epilogue constants for dims dd..dd+3 (b_gates folded in)
    const int dd = kb * 4;
    f32x4 biasI, biasF, biasC, biasO, pp0, pp1, pp2, wl4;
    #pragma unroll
    for (int e = 0; e < 4; ++e) {
        biasI[e] = bx[dd + e]      + bh[dd + e]      + b_gates[dd + e];
        biasF[e] = bx[16 + dd + e] + bh[16 + dd + e] + b_gates[16 + dd + e];
        biasC[e] = bx[32 + dd + e] + bh[32 + dd + e] + b_gates[32 + dd + e];
        biasO[e] = bx[48 + dd + e] + bh[48 + dd + e] + b_gates[48 + dd + e];
        pp0[e] = w_peep[dd + e]; pp1[e] = w_peep[16 + dd + e]; pp2[e] = w_peep[32 + dd + e];
        wl4[e] = W_lin[dd + e];
    }
    const float bl = b_lin[0];

    const unsigned blockBase = (unsigned)blockIdx.x * NPB;
    const unsigned gb0   = blockBase + (unsigned)wave * 16u;  // wave's first node
    const unsigned node0 = gb0 + (unsigned)q;

    // per-lane X pointer (B-frag): x rows for kb==0, h rows otherwise
    // (kb==3 loads h[...+0] = finite garbage; multiplied by zero W rows)
    const float* aptr;
    unsigned astride;
    if (kb == 0) { aptr = x + (size_t)node0 * 8;                        astride = 64u * 8;  }
    else         { aptr = h + (size_t)node0 * 16 + ((kb == 2) ? 8 : 0); astride = 64u * 16; }

    unsigned co = node0 * 16u + (unsigned)dd;  // c / h_new / c_new float4 offset
    unsigned ro = node0;                       // out offset (kb==0 lanes store)
    float* hob = dout + (size_t)n;        // h_new base
    float* cob = dout + (size_t)n * 17;   // c_new base

    // compute one iteration from registers A0,A1,CV; stores at current co/ro
#define COMPUTE(A0, A1, CV)                                                    \
    {                                                                          \
        bf16x8 xf;                                                             \
        xf[0] = f2bf((A0).x); xf[1] = f2bf((A0).y);                            \
        xf[2] = f2bf((A0).z); xf[3] = f2bf((A0).w);                            \
        xf[4] = f2bf((A1).x); xf[5] = f2bf((A1).y);                            \
        xf[6] = f2bf((A1).z); xf[7] = f2bf((A1).w);                            \
        f32x4 accI = biasI, accF = biasF, accC = biasC, accO = biasO;          \
        accI = __builtin_amdgcn_mfma_f32_16x16x32_bf16(wfrag[0], xf, accI, 0, 0, 0); \
        accF = __builtin_amdgcn_mfma_f32_16x16x32_bf16(wfrag[1], xf, accF, 0, 0, 0); \
        accC = __builtin_amdgcn_mfma_f32_16x16x32_bf16(wfrag[2], xf, accC, 0, 0, 0); \
        accO = __builtin_amdgcn_mfma_f32_16x16x32_bf16(wfrag[3], xf, accO, 0, 0, 0); \
        f32x4 iv = sig4(pp0 * (CV) + accI);                                    \
        f32x4 fv = sig4(pp1 * (CV) + accF);                                    \
        f32x4 tv = tanh4(accC);                                                \
        f32x4 cn = fv * (CV) + iv * tv;                                        \
        f32x4 ov = sig4(pp2 * cn + accO);                                      \
        f32x4 hn = ov * tanh4(cn);                                             \
        __builtin_nontemporal_store(hn, reinterpret_cast<f32x4*>(hob + co));   \
        __builtin_nontemporal_store(cn, reinterpret_cast<f32x4*>(cob + co));   \
        f32x4 rr = max4z(hn) * wl4;                                            \
        float os = (rr[0] + rr[1]) + (rr[2] + rr[3]);                          \
        os += __shfl_xor(os, 16);                                              \
        os += __shfl_xor(os, 32);                                              \
        if (kb == 0) dout[ro] = os + bl;                                       \
    }

    if (blockBase + NPB <= (unsigned)n) {
        // full block: 1-deep pipelined — issue it+1's loads before it's compute
        float4 a0 = *reinterpret_cast<const float4*>(aptr);
        float4 a1 = *reinterpret_cast<const float4*>(aptr + 4);
        f32x4  cv = *reinterpret_cast<const f32x4*>(c + co);
        #pragma unroll 1
        for (int it = 0; it < IW - 1; ++it) {
            const float* nap = aptr + astride;
            float4 na0 = *reinterpret_cast<const float4*>(nap);
            float4 na1 = *reinterpret_cast<const float4*>(nap + 4);
            f32x4  ncv = *reinterpret_cast<const f32x4*>(c + co + 1024u);
            COMPUTE(a0, a1, cv);
            a0 = na0; a1 = na1; cv = ncv;
            aptr = nap; co += 1024u; ro += 64u;
        }
        COMPUTE(a0, a1, cv);
    } else {
        // tail block (at most one): group-granular bounds check (n % 16 == 0)
        #pragma unroll 1
        for (int it = 0; it < IW; ++it) {
            if (gb0 + (unsigned)(it * 64) >= (unsigned)n) break;
            float4 a0 = *reinterpret_cast<const float4*>(aptr);
            float4 a1 = *reinterpret_cast<const float4*>(aptr + 4);
            f32x4  cv = *reinterpret_cast<const f32x4*>(c + co);
            COMPUTE(a0, a1, cv);
            aptr += astride; co += 1024u; ro += 64u;
        }
    }
#undef COMPUTE
}

extern "C" void kernel_launch(void* const* d_in, const int* in_sizes, int n_in,
                              void* d_out, int out_size, void* d_ws, size_t ws_size,
                              hipStream_t stream) {
    const float* x       = (const float*)d_in[0];
    // d_in[1] = edge_index (int64, unused), d_in[2] = edge_attr (unused)
    const float* h       = (const float*)d_in[3];
    const float* c       = (const float*)d_in[4];
    const float* Wx      = (const float*)d_in[5];
    const float* bx      = (const float*)d_in[6];
    const float* Wh      = (const float*)d_in[7];
    const float* bh      = (const float*)d_in[8];
    const float* w_peep  = (const float*)d_in[9];
    const float* b_gates = (const float*)d_in[10];
    const float* W_lin   = (const float*)d_in[11];
    const float* b_lin   = (const float*)d_in[12];
    float* out = (float*)d_out;

    const int n = in_sizes[0] / 8;  // N = 1,000,000
    const int blocks = (n + NPB - 1) / NPB;
    lstm_mfma_kernel<<<blocks, 256, 0, stream>>>(
        x, h, c, Wx, bx, Wh, bh, w_peep, b_gates, W_lin, b_lin, out, n);
}

// Round 9
// 52.325 us; speedup vs baseline: 1.4290x; 1.0242x over previous
//
#include <hip/hip_runtime.h>
#include <hip/hip_bf16.h>
#include <math.h>

// GConvLSTM cell via MFMA (graph inputs are dead code in the reference).
// Transposed gate GEMM (R7 layout): g^T = W^T @ [x|h]^T via
// mfma_f32_16x16x32_bf16(A=W-frag, B=X-frag); lane (q=lane&15, kb=lane>>4)
// owns node gb0+q, dims kb*4..kb*4+3 of every gate -> all c/h_new/c_new
// accesses are wave-contiguous float4; out-reduce = in-lane 4-dot + 2 shfl.
// W K-rows 24..31 are zero, so kb==3 X-garbage contributes 0 (R4-proven).
// R9 vs R8: 2-DEEP software pipeline (R8's 1-deep: 74.8->53.6us, matched
// prediction; still latency-bound at ~23% VALUBusy). Two named register sets
// (A=even iter, B=odd iter); prefetch iter n+2 before computing iter n ->
// load-to-use distance ~2 compute bodies (~700cy) vs ~900cy HBM latency.
// Named sets (no runtime-indexed arrays -> no scratch, rule #20).
// h_new/c_new stores stay nontemporal.
// d_out layout: [N] out | [N*16] h_new | [N*16] c_new.  Requires n % 16 == 0.

typedef short bf16x8 __attribute__((ext_vector_type(8)));
typedef float f32x4 __attribute__((ext_vector_type(4)));

#define LOG2E 1.44269504088896f

__device__ __forceinline__ float sig1(float v) {
    return __builtin_amdgcn_rcpf(1.0f + __builtin_amdgcn_exp2f(-LOG2E * v));
}
__device__ __forceinline__ float tanh1(float v) {
    return 1.0f - 2.0f * __builtin_amdgcn_rcpf(__builtin_amdgcn_exp2f((2.0f * LOG2E) * v) + 1.0f);
}
__device__ __forceinline__ f32x4 sig4(f32x4 v) {
    f32x4 r; r[0]=sig1(v[0]); r[1]=sig1(v[1]); r[2]=sig1(v[2]); r[3]=sig1(v[3]); return r;
}
__device__ __forceinline__ f32x4 tanh4(f32x4 v) {
    f32x4 r; r[0]=tanh1(v[0]); r[1]=tanh1(v[1]); r[2]=tanh1(v[2]); r[3]=tanh1(v[3]); return r;
}
__device__ __forceinline__ short f2bf(float f) {
    __bf16 b = (__bf16)f;          // pairs fuse to v_cvt_pk_bf16_f32
    short s; __builtin_memcpy(&s, &b, 2); return s;
}
__device__ __forceinline__ f32x4 max4z(f32x4 a) {
    f32x4 r; r[0]=fmaxf(a[0],0.f); r[1]=fmaxf(a[1],0.f); r[2]=fmaxf(a[2],0.f); r[3]=fmaxf(a[3],0.f); return r;
}

#define IW 8                       // 64-node tiles per block (even!)
#define NPB (64 * IW)              // 512 nodes per block

__global__ __launch_bounds__(256) void lstm_mfma_kernel(
    const float* __restrict__ x,       // N x 8
    const float* __restrict__ h,       // N x 16
    const float* __restrict__ c,       // N x 16
    const float* __restrict__ Wx,      // 8 x 64
    const float* __restrict__ bx,      // 64
    const float* __restrict__ Wh,      // 16 x 64
    const float* __restrict__ bh,      // 64
    const float* __restrict__ w_peep,  // 3 x 16
    const float* __restrict__ b_gates, // 4 x 16
    const float* __restrict__ W_lin,   // 16
    const float* __restrict__ b_lin,   // 1
    float* __restrict__ dout,
    int n)
{
    const int lane = threadIdx.x & 63;
    const int wave = threadIdx.x >> 6;
    const int q  = lane & 15;   // A-role: dim; B/D-role: node offset
    const int kb = lane >> 4;   // k-block (8 k's each); D-role: dim block

    // ---- weight A-fragment: wfrag[t][e] = W[kb*8+e][t*16+q], W = [Wx; Wh; 0pad]
    // Rows 24..31 MUST be exactly 0 (kb==3 X-frag is garbage and relies on it).
    bf16x8 wfrag[4];
    #pragma unroll
    for (int t = 0; t < 4; ++t) {
        #pragma unroll
        for (int e = 0; e < 8; ++e) {
            const int r = kb * 8 + e;
            float w = 0.0f;
            if (r < 8)        w = Wx[r * 64 + t * 16 + q];
            else if (r < 24)  w = Wh[(r - 8) * 64 + t * 16 + q];
            wfrag[t][e] = f2bf(w);
        }
    }

    // ---- per-lane epilogue constants for dims dd..dd+3 (b_gates folded in)
    const int dd = kb * 4;
    f32x4 biasI, biasF, biasC, biasO, pp0, pp1, pp2, wl4;
    #pragma unroll
    for (int e = 0; e < 4; ++e) {
        biasI[e] = bx[dd + e]      + bh[dd + e]      + b_gates[dd + e];
        biasF[e] = bx[16 + dd + e] + bh[16 + dd + e] + b_gates[16 + dd + e];
        biasC[e] = bx[32 + dd + e] + bh[32 + dd + e] + b_gates[32 + dd + e];
        biasO[e] = bx[48 + dd + e] + bh[48 + dd + e] + b_gates[48 + dd + e];
        pp0[e] = w_peep[dd + e]; pp1[e] = w_peep[16 + dd + e]; pp2[e] = w_peep[32 + dd + e];
        wl4[e] = W_lin[dd + e];
    }
    const float bl = b_lin[0];

    const unsigned blockBase = (unsigned)blockIdx.x * NPB;
    const unsigned gb0   = blockBase + (unsigned)wave * 16u;  // wave's first node
    const unsigned node0 = gb0 + (unsigned)q;

    // per-lane X pointer (B-frag): x rows for kb==0, h rows otherwise
    // (kb==3 loads h[...+0] = finite garbage; multiplied by zero W rows)
    const float* aptr;
    unsigned astride;
    if (kb == 0) { aptr = x + (size_t)node0 * 8;                        astride = 64u * 8;  }
    else         { aptr = h + (size_t)node0 * 16 + ((kb == 2) ? 8 : 0); astride = 64u * 16; }

    const unsigned co0 = node0 * 16u + (unsigned)dd;  // c / h_new / c_new float4 offset
    const unsigned ro0 = node0;                       // out offset (kb==0 lanes store)
    float* hob = dout + (size_t)n;        // h_new base
    float* cob = dout + (size_t)n * 17;   // c_new base

    // compute one iteration from registers A0,A1,CV; stores at CO/RO
#define COMPUTE(A0, A1, CV, CO, RO)                                            \
    {                                                                          \
        bf16x8 xf;                                                             \
        xf[0] = f2bf((A0).x); xf[1] = f2bf((A0).y);                            \
        xf[2] = f2bf((A0).z); xf[3] = f2bf((A0).w);                            \
        xf[4] = f2bf((A1).x); xf[5] = f2bf((A1).y);                            \
        xf[6] = f2bf((A1).z); xf[7] = f2bf((A1).w);                            \
        f32x4 accI = biasI, accF = biasF, accC = biasC, accO = biasO;          \
        accI = __builtin_amdgcn_mfma_f32_16x16x32_bf16(wfrag[0], xf, accI, 0, 0, 0); \
        accF = __builtin_amdgcn_mfma_f32_16x16x32_bf16(wfrag[1], xf, accF, 0, 0, 0); \
        accC = __builtin_amdgcn_mfma_f32_16x16x32_bf16(wfrag[2], xf, accC, 0, 0, 0); \
        accO = __builtin_amdgcn_mfma_f32_16x16x32_bf16(wfrag[3], xf, accO, 0, 0, 0); \
        f32x4 iv = sig4(pp0 * (CV) + accI);                                    \
        f32x4 fv = sig4(pp1 * (CV) + accF);                                    \
        f32x4 tv = tanh4(accC);                                                \
        f32x4 cn = fv * (CV) + iv * tv;                                        \
        f32x4 ov = sig4(pp2 * cn + accO);                                      \
        f32x4 hn = ov * tanh4(cn);                                             \
        __builtin_nontemporal_store(hn, reinterpret_cast<f32x4*>(hob + (CO))); \
        __builtin_nontemporal_store(cn, reinterpret_cast<f32x4*>(cob + (CO))); \
        f32x4 rr = max4z(hn) * wl4;                                            \
        float os = (rr[0] + rr[1]) + (rr[2] + rr[3]);                          \
        os += __shfl_xor(os, 16);                                              \
        os += __shfl_xor(os, 32);                                              \
        if (kb == 0) dout[RO] = os + bl;                                       \
    }

    if (blockBase + NPB <= (unsigned)n) {
        // full block: 2-deep pipeline with two named register sets.
        // A = even iterations (0,2,4,6), B = odd iterations (1,3,5,7).
        const float* apA = aptr;
        const float* apB = aptr + astride;
        unsigned coA = co0,        coB = co0 + 1024u;
        unsigned roA = ro0,        roB = ro0 + 64u;
        const unsigned astep = 2u * astride;

        float4 a0A = *reinterpret_cast<const float4*>(apA);
        float4 a1A = *reinterpret_cast<const float4*>(apA + 4);
        f32x4  cvA = *reinterpret_cast<const f32x4*>(c + coA);
        float4 a0B = *reinterpret_cast<const float4*>(apB);
        float4 a1B = *reinterpret_cast<const float4*>(apB + 4);
        f32x4  cvB = *reinterpret_cast<const f32x4*>(c + coB);

        #pragma unroll 1
        for (int k = 0; k < (IW - 2) / 2; ++k) {
            // prefetch iter 2k+2 (next A), then compute iter 2k (A)
            const float* npA = apA + astep;
            float4 t0 = *reinterpret_cast<const float4*>(npA);
            float4 t1 = *reinterpret_cast<const float4*>(npA + 4);
            f32x4  tc = *reinterpret_cast<const f32x4*>(c + coA + 2048u);
            COMPUTE(a0A, a1A, cvA, coA, roA);
            a0A = t0; a1A = t1; cvA = tc;
            apA = npA; coA += 2048u; roA += 128u;

            // prefetch iter 2k+3 (next B), then compute iter 2k+1 (B)
            const float* npB = apB + astep;
            float4 u0 = *reinterpret_cast<const float4*>(npB);
            float4 u1 = *reinterpret_cast<const float4*>(npB + 4);
            f32x4  uc = *reinterpret_cast<const f32x4*>(c + coB + 2048u);
            COMPUTE(a0B, a1B, cvB, coB, roB);
            a0B = u0; a1B = u1; cvB = uc;
            apB = npB; coB += 2048u; roB += 128u;
        }
        COMPUTE(a0A, a1A, cvA, coA, roA);   // iter IW-2
        COMPUTE(a0B, a1B, cvB, coB, roB);   // iter IW-1
    } else {
        // tail block (at most one): group-granular bounds check (n % 16 == 0)
        const float* ap = aptr;
        unsigned co = co0, ro = ro0;
        #pragma unroll 1
        for (int it = 0; it < IW; ++it) {
            if (gb0 + (unsigned)(it * 64) >= (unsigned)n) break;
            float4 a0 = *reinterpret_cast<const float4*>(ap);
            float4 a1 = *reinterpret_cast<const float4*>(ap + 4);
            f32x4  cv = *reinterpret_cast<const f32x4*>(c + co);
            COMPUTE(a0, a1, cv, co, ro);
            ap += astride; co += 1024u; ro += 64u;
        }
    }
#undef COMPUTE
}

extern "C" void kernel_launch(void* const* d_in, const int* in_sizes, int n_in,
                              void* d_out, int out_size, void* d_ws, size_t ws_size,
                              hipStream_t stream) {
    const float* x       = (const float*)d_in[0];
    // d_in[1] = edge_index (int64, unused), d_in[2] = edge_attr (unused)
    const float* h       = (const float*)d_in[3];
    const float* c       = (const float*)d_in[4];
    const float* Wx      = (const float*)d_in[5];
    const float* bx      = (const float*)d_in[6];
    const float* Wh      = (const float*)d_in[7];
    const float* bh      = (const float*)d_in[8];
    const float* w_peep  = (const float*)d_in[9];
    const float* b_gates = (const float*)d_in[10];
    const float* W_lin   = (const float*)d_in[11];
    const float* b_lin   = (const float*)d_in[12];
    float* out = (float*)d_out;

    const int n = in_sizes[0] / 8;  // N = 1,000,000
    const int blocks = (n + NPB - 1) / NPB;
    lstm_mfma_kernel<<<blocks, 256, 0, stream>>>(
        x, h, c, Wx, bx, Wh, bh, w_peep, b_gates, W_lin, b_lin, out, n);
}